// Round 6
// baseline (223.687 us; speedup 1.0000x reference)
//
#include <hip/hip_runtime.h>

// LNCC DEBUG1: num = (tp_sum - (p_sum/729)*t_sum)^2 + 1e-5, 9^3 box sums, SAME zero pad.
//
// R10 = R9 resubmitted verbatim (previous bench failed on infra: "container failed
// twice" — no kernel signal). R9 = R8 champion (110 us) with ONE surgical reorder:
// rowsum moves from the pre-bar1 segment into the post-bar2 shadow. After bar2,
// colsum(i) has already consumed rowT(i) (its ds_reads drained by its own
// lgkmcnt(0) before bar2 -> WAR safe), so rowsum(i+1) runs fused with finalize at
// iteration end, interleaved with gather's independent chain. Per-plane serial
// skeleton shrinks from
//   loads -> rowsum+4writes -> bar1 -> colsum -> bar2 -> gather||finalize
// to
//   loads -> bar1 -> colsum -> bar2 -> gather || finalize+rowsum+writes.
// Guard identity vn(i) == vi(i+1): stale rowT is never read. `cur` registers are
// eliminated (finalize feeds rowsum directly): -12 live VGPRs, away from the 64
// cliff (2 blocks/CU requires VGPR<=64; R8 was 60/64).
// Barriers, stage bodies, thread roles, LDS layout: byte-identical to R8.

#define N 192
#define RSTRIDE 46   // rowT stride: 2-way banks (free) + 8B-aligned float2 reads

// LDS-only barrier: drain LDS ops, then barrier. No vmcnt drain (prefetch stays in flight).
#define LDS_BARRIER() asm volatile("s_waitcnt lgkmcnt(0)\n\ts_barrier" ::: "memory")

__global__ __launch_bounds__(1024, 4)
void lncc_kernel(const float* __restrict__ t_in,
                 const float* __restrict__ p_in,
                 float* __restrict__ out)
{
    // rowT[f][x][ry]: transposed x-blurred row sums (single-buffered)
    __shared__ __align__(16) float rowT[3 * 32 * RSTRIDE];   // 17.3 KB
    // pcol[f][y][x]: per-plane 2D (9x9) box sums
    __shared__ float pcol[3 * 32 * 32];                      // 12 KB

    // ---- work assignment: 512 blocks = 72 xy tiles x {8 or 7} z-chunks ----
    const int bid = blockIdx.x;
    int xy, Z, z0;
    if (bid < 64) {                 // tiles 0..7: 8 chunks of Z=24
        xy = bid >> 3;
        Z  = 24;
        z0 = (bid & 7) * 24;
    } else {                        // tiles 8..71: 7 chunks (28,28,28,27,27,27,27)
        const int q  = bid - 64;
        xy = 8 + q / 7;
        const int zi = q % 7;
        if (zi < 3) { Z = 28; z0 = zi * 28; }
        else        { Z = 27; z0 = 84 + (zi - 3) * 27; }
    }
    const int b  = xy / 36;
    const int t6 = xy % 36;
    const int y0 = (t6 / 6) * 32, x0 = (t6 % 6) * 32;
    const int tid = threadIdx.x;

    // ---- L (row-sum) decode: 3 fields x 40 rows x 8 x-quads = 960 slots (15 waves)
    const int  lf   = tid / 320;          // 0=t 1=p 2=tp (wave-uniform: 320=5*64)
    const int  ls   = tid - lf * 320;
    const int  lry  = ls >> 3;            // raw row 0..39
    const int  lxq  = ls & 7;             // x quad 0..7
    const int  lgy  = y0 - 4 + lry;
    const int  lgx0 = x0 - 4 + 4 * lxq;   // 16B-aligned quad base
    const bool lactive = (tid < 960);
    const bool lyok = ((unsigned)lgy < (unsigned)N);

    // ---- C (col-sum) decode: 3 fields x 8 y-quads x 32 x = 768 slots (12 waves)
    const int  cf  = tid >> 8;
    const int  cyq = (tid >> 5) & 7;
    const int  cx  = tid & 31;
    const bool cactive = (tid < 768);

    // ---- G decode: thread owns output column (gx,gy)
    const int gx = tid & 31;
    const int gy = tid >> 5;

    const size_t plane = (size_t)N * N;
    const float* tb = t_in + (size_t)b * N * plane;
    const float* pb = p_in + (size_t)b * N * plane;
    float*       ob = out  + (size_t)b * N * plane
                           + (size_t)(y0 + gy) * N + (x0 + gx);

    // loop-invariant row base pointers (y clamped; loads stay guarded by lactive&&lyok)
    const int lgyc = lyok ? lgy : 0;
    const float* const trow = tb + (size_t)lgyc * N;
    const float* const prow = pb + (size_t)lgyc * N;
    const float* const arow = (lf == 1) ? prow : trow;   // wave-uniform a-source select

    float ring_t[9], ring_p[9], ring_tp[9];
    float sum_t = 0.f, sum_p = 0.f, sum_tp = 0.f;
    #pragma unroll
    for (int i = 0; i < 9; ++i) { ring_t[i] = 0.f; ring_p[i] = 0.f; ring_tp[i] = 0.f; }

    const float4 z4 = make_float4(0.f, 0.f, 0.f, 0.f);

    // ---- prologue: load, finalize, rowsum, write plane 0 (one exposed latency) ----
    {
        const int zp0 = z0 - 4;
        float4 fa0 = z4, fa1 = z4, fa2 = z4, fc0 = z4, fc1 = z4, fc2 = z4;
        if (((unsigned)zp0 < (unsigned)N) && lactive && lyok) {
            const float* ar = arow + (size_t)zp0 * plane;
            const float* cr = prow + (size_t)zp0 * plane;
            const int g0 = lgx0, g1 = lgx0 + 4, g2 = lgx0 + 8;
            if ((unsigned)g0 < (unsigned)N) {
                fa0 = *(const float4*)(ar + g0);
                if (lf == 2) fc0 = *(const float4*)(cr + g0);
            }
            if ((unsigned)g1 < (unsigned)N) {
                fa1 = *(const float4*)(ar + g1);
                if (lf == 2) fc1 = *(const float4*)(cr + g1);
            }
            if ((unsigned)g2 < (unsigned)N) {
                fa2 = *(const float4*)(ar + g2);
                if (lf == 2) fc2 = *(const float4*)(cr + g2);
            }
        }
        if (lactive) {
            float4 A0 = fa0, A1 = fa1, A2 = fa2;
            if (lf == 2) {
                A0.x *= fc0.x; A0.y *= fc0.y; A0.z *= fc0.z; A0.w *= fc0.w;
                A1.x *= fc1.x; A1.y *= fc1.y; A1.z *= fc1.z; A1.w *= fc1.w;
                A2.x *= fc2.x; A2.y *= fc2.y; A2.z *= fc2.z; A2.w *= fc2.w;
            }
            const float v0 = A0.x, v1 = A0.y, v2  = A0.z, v3  = A0.w;
            const float v4 = A1.x, v5 = A1.y, v6  = A1.z, v7  = A1.w;
            const float v8 = A2.x, v9 = A2.y, v10 = A2.z, v11 = A2.w;
            float s0 = ((v0+v1) + (v2+v3)) + ((v4+v5) + (v6+v7)) + v8;
            float s1 = s0 - v0 + v9;
            float s2 = s1 - v1 + v10;
            float s3 = s2 - v2 + v11;
            float* wp = &rowT[(lf * 32 + 4 * lxq) * RSTRIDE + lry];
            wp[0]           = s0;
            wp[RSTRIDE]     = s1;
            wp[2 * RSTRIDE] = s2;
            wp[3 * RSTRIDE] = s3;
        }
    }

    #pragma unroll 1
    for (int k = 0; k < 4; ++k) {
      #pragma unroll
      for (int r = 0; r < 9; ++r) {
        const int i  = k * 9 + r;
        const int zp = z0 - 4 + i;           // plane i
        const int zn = zp + 1;               // plane i+1
        const bool vi = (i < Z + 8)     && ((unsigned)zp < (unsigned)N);
        const bool vn = (i + 1 < Z + 8) && ((unsigned)zn < (unsigned)N);

        // ---- 1. issue loads for plane i+1 (consumed at step 4) ----
        float4 fa0 = z4, fa1 = z4, fa2 = z4, fc0 = z4, fc1 = z4, fc2 = z4;
        if (vn && lactive && lyok) {
            const float* ar = arow + (size_t)zn * plane;
            const float* cr = prow + (size_t)zn * plane;
            const int g0 = lgx0, g1 = lgx0 + 4, g2 = lgx0 + 8;
            if ((unsigned)g0 < (unsigned)N) {
                fa0 = *(const float4*)(ar + g0);
                if (lf == 2) fc0 = *(const float4*)(cr + g0);
            }
            if ((unsigned)g1 < (unsigned)N) {
                fa1 = *(const float4*)(ar + g1);
                if (lf == 2) fc1 = *(const float4*)(cr + g1);
            }
            if ((unsigned)g2 < (unsigned)N) {
                fa2 = *(const float4*)(ar + g2);
                if (lf == 2) fc2 = *(const float4*)(cr + g2);
            }
        }
        LDS_BARRIER();   // bar1: seals rowT(i) written at end of prev iter / prologue

        // ---- 2. ColSum(plane i): rowT -> pcol ----
        if (vi && cactive) {
            const float* rb = &rowT[(cf * 32 + cx) * RSTRIDE + 4 * cyq];
            const float2 u0 = *(const float2*)(rb + 0);
            const float2 u1 = *(const float2*)(rb + 2);
            const float2 u2 = *(const float2*)(rb + 4);
            const float2 u3 = *(const float2*)(rb + 6);
            const float2 u4 = *(const float2*)(rb + 8);
            const float2 u5 = *(const float2*)(rb + 10);
            const float w0=u0.x, w1=u0.y, w2=u1.x,  w3=u1.y;
            const float w4=u2.x, w5=u2.y, w6=u3.x,  w7=u3.y;
            const float w8=u4.x, w9=u4.y, w10=u5.x, w11=u5.y;
            float c0 = ((w0+w1)+(w2+w3)) + ((w4+w5)+(w6+w7)) + w8;
            float c1 = c0 - w0 + w9;
            float c2 = c1 - w1 + w10;
            float c3 = c2 - w2 + w11;
            float* pc = &pcol[cf * 1024 + (4 * cyq) * 32 + cx];
            pc[0]  = c0;
            pc[32] = c1;
            pc[64] = c2;
            pc[96] = c3;
        }
        LDS_BARRIER();   // bar2: seals pcol(i); rowT now dead -> writable below

        // ---- 3. Gather(plane i), z-ring (slot r == i%9), output ----
        float Pt = 0.f, Pp = 0.f, Ptp = 0.f;
        if (vi) {
            Pt  = pcol[       gy * 32 + gx];
            Pp  = pcol[1024 + gy * 32 + gx];
            Ptp = pcol[2048 + gy * 32 + gx];
        }
        sum_t  += Pt  - ring_t[r];  ring_t[r]  = Pt;
        sum_p  += Pp  - ring_p[r];  ring_p[r]  = Pp;
        sum_tp += Ptp - ring_tp[r]; ring_tp[r] = Ptp;
        if (i >= 8 && i < Z + 8) {
            const float cross = sum_tp - (sum_p * (1.0f / 729.0f)) * sum_t;
            ob[(size_t)(z0 + i - 8) * plane] = cross * cross + 1e-5f;
        }

        // ---- 4. finalize + RowSum(plane i+1) -> rowT (post-bar2 shadow) ----
        if (vn && lactive) {
            float4 A0 = fa0, A1 = fa1, A2 = fa2;
            if (lf == 2) {
                A0.x *= fc0.x; A0.y *= fc0.y; A0.z *= fc0.z; A0.w *= fc0.w;
                A1.x *= fc1.x; A1.y *= fc1.y; A1.z *= fc1.z; A1.w *= fc1.w;
                A2.x *= fc2.x; A2.y *= fc2.y; A2.z *= fc2.z; A2.w *= fc2.w;
            }
            const float v0 = A0.x, v1 = A0.y, v2  = A0.z, v3  = A0.w;
            const float v4 = A1.x, v5 = A1.y, v6  = A1.z, v7  = A1.w;
            const float v8 = A2.x, v9 = A2.y, v10 = A2.z, v11 = A2.w;
            float s0 = ((v0+v1) + (v2+v3)) + ((v4+v5) + (v6+v7)) + v8;
            float s1 = s0 - v0 + v9;
            float s2 = s1 - v1 + v10;
            float s3 = s2 - v2 + v11;
            float* wp = &rowT[(lf * 32 + 4 * lxq) * RSTRIDE + lry];
            wp[0]           = s0;
            wp[RSTRIDE]     = s1;
            wp[2 * RSTRIDE] = s2;
            wp[3 * RSTRIDE] = s3;
        }
      }
    }
}

extern "C" void kernel_launch(void* const* d_in, const int* in_sizes, int n_in,
                              void* d_out, int out_size, void* d_ws, size_t ws_size,
                              hipStream_t stream) {
    const float* y_true = (const float*)d_in[0];
    const float* y_pred = (const float*)d_in[1];
    float* out = (float*)d_out;
    dim3 grid(512);
    dim3 block(1024);
    hipLaunchKernelGGL(lncc_kernel, grid, block, 0, stream, y_true, y_pred, out);
}